// Round 1
// baseline (336.146 us; speedup 1.0000x reference)
//
#include <hip/hip_runtime.h>

#define N1v 2000
#define N2v 4000
#define DIN 30
#define DZ 32
#define DQ 94
#define INV_TEMP 0.17677669529663687f  // 1/sqrt(32)

__device__ __forceinline__ float wave_reduce_sum(float v) {
#pragma unroll
    for (int off = 32; off; off >>= 1) v += __shfl_xor(v, off, 64);
    return v;
}
__device__ __forceinline__ float wave_reduce_max(float v) {
#pragma unroll
    for (int off = 32; off; off >>= 1) v = fmaxf(v, __shfl_xor(v, off, 64));
    return v;
}

// ---------------------------------------------------------------------------
// Kernel 1: per-landmark projections + features + delay score
// thread t -> (row = t/32, c = t%32)
// ---------------------------------------------------------------------------
__global__ __launch_bounds__(256) void prep_kernel(
    const float* __restrict__ lm_X, const float* __restrict__ lm_Y,
    const float* __restrict__ lm_delay,
    const float* __restrict__ att_kw, const float* __restrict__ att_kb,
    const float* __restrict__ pred_kw, const float* __restrict__ pred_kb,
    const float* __restrict__ pred_vw, const float* __restrict__ pred_vb,
    const float* __restrict__ gamma_1, const float* __restrict__ alpha,
    const float* __restrict__ beta,
    float* __restrict__ lm_feature, float* __restrict__ k_att,
    float* __restrict__ pk, float* __restrict__ pv,
    float* __restrict__ delay_score)
{
    int t = blockIdx.x * blockDim.x + threadIdx.x;
    if (t >= N1v * DZ) return;
    int row = t >> 5, c = t & 31;
    const float* xr = lm_X + row * DIN;
    float kacc = att_kb[c], pacc = pred_kb[c];
#pragma unroll
    for (int d = 0; d < DIN; ++d) {
        float x = xr[d];
        kacc += x * att_kw[d * DZ + c];
        pacc += x * pred_kw[d * DZ + c];
    }
    k_att[t] = kacc;
    pk[t] = pacc;
    lm_feature[t] = (c < DIN) ? xr[c] : lm_Y[row * 2 + (c - DIN)];
    if (c < 2) {
        pv[row * 2 + c] = lm_Y[row * 2] * pred_vw[c] +
                          lm_Y[row * 2 + 1] * pred_vw[2 + c] + pred_vb[c];
    }
    if (c == 0) {
        delay_score[row] = __expf(-gamma_1[0] * (alpha[0] * lm_delay[row] + beta[0]));
    }
}

// ---------------------------------------------------------------------------
// Kernel 2: router_0 (column mean), router_1 = h_r @ w1_w + w1_b
//   h_r = (router_0 + sum_j ds_j * lm_feature_j) / (1 + sum_j ds_j)
// one block, 256 threads
// ---------------------------------------------------------------------------
__global__ __launch_bounds__(256) void router_kernel(
    const float* __restrict__ lm_feature, const float* __restrict__ delay_score,
    const float* __restrict__ w1_w, const float* __restrict__ w1_b,
    float* __restrict__ router_0, float* __restrict__ router_1)
{
    __shared__ float ps[8][DZ];
    __shared__ float pw[8][DZ];
    __shared__ float pd[8];
    __shared__ float hr[DZ];
    int t = threadIdx.x;
    int c = t & 31, g = t >> 5;
    float s = 0.f, wsum = 0.f, sd = 0.f;
    for (int r = g; r < N1v; r += 8) {
        float f = lm_feature[r * DZ + c];
        float ds = delay_score[r];
        s += f;
        wsum += ds * f;
        if (c == 0) sd += ds;
    }
    ps[g][c] = s;
    pw[g][c] = wsum;
    if (c == 0) pd[g] = sd;
    __syncthreads();
    if (t < DZ) {
        float S = 0.f, W = 0.f, Sd = 0.f;
#pragma unroll
        for (int g2 = 0; g2 < 8; ++g2) { S += ps[g2][t]; W += pw[g2][t]; Sd += pd[g2]; }
        float r0 = S / (float)N1v;
        router_0[t] = r0;
        hr[t] = (r0 + W) / (1.f + Sd);
    }
    __syncthreads();
    if (t < DZ) {
        float acc = w1_b[t];
#pragma unroll
        for (int d = 0; d < DZ; ++d) acc += hr[d] * w1_w[d * DZ + t];
        router_1[t] = acc;
    }
}

// ---------------------------------------------------------------------------
// Kernel 3: fully fused per-target-row pipeline. 1 wave = 1 target row,
// 4 waves (256 thr) per block, 1000 blocks.
// ---------------------------------------------------------------------------
__global__ __launch_bounds__(256) void main_kernel(
    const float* __restrict__ tg_X, const float* __restrict__ tg_delay,
    const float* __restrict__ att_qw, const float* __restrict__ att_qb,
    const float* __restrict__ w1_w, const float* __restrict__ w1_b,
    const float* __restrict__ w2_w, const float* __restrict__ w2_b,
    const float* __restrict__ pred_qw, const float* __restrict__ pred_qb,
    const float* __restrict__ gamma_2, const float* __restrict__ gamma_3,
    const float* __restrict__ alpha, const float* __restrict__ beta,
    const float* __restrict__ lm_feature, const float* __restrict__ k_att,
    const float* __restrict__ pk, const float* __restrict__ pv,
    const float* __restrict__ router_0, const float* __restrict__ router_1,
    float* __restrict__ y_out, float* __restrict__ ftf_out)
{
    __shared__ float sc[4][N1v];     // per-wave score/e buffer (32 KB)
    __shared__ float vbuf[4][128];   // per-wave small vectors (2 KB)
    const int wv = threadIdx.x >> 6;
    const int lane = threadIdx.x & 63;
    const int i = blockIdx.x * 4 + wv;   // N2v = 4000 = 1000*4, always valid
    const float* xr = tg_X + i * DIN;

    // ---- Phase A: q = (tg_X[i] @ att_qw + att_qb) / TEMP -> vbuf ----
    if (lane < DZ) {
        float acc = att_qb[lane];
#pragma unroll
        for (int d = 0; d < DIN; ++d) acc += xr[d] * att_qw[d * DZ + lane];
        vbuf[wv][lane] = acc * INV_TEMP;
    }
    __syncthreads();
    float4 qreg[8];
#pragma unroll
    for (int u = 0; u < 8; ++u) qreg[u] = *(const float4*)&vbuf[wv][u * 4];

    // ---- Phase B: scores vs k_att, row softmax numerator into sc ----
    float m = -1e30f;
#pragma unroll 2
    for (int t = 0; t < 31; ++t) {
        int j = t * 64 + lane;
        const float4* kr = (const float4*)(k_att + j * DZ);
        float acc = 0.f;
#pragma unroll
        for (int u = 0; u < 8; ++u) {
            float4 kk = kr[u];
            acc += kk.x * qreg[u].x + kk.y * qreg[u].y + kk.z * qreg[u].z + kk.w * qreg[u].w;
        }
        sc[wv][j] = acc;
        m = fmaxf(m, acc);
    }
    if (lane < 16) {  // tail: j = 1984 + lane
        int j = 31 * 64 + lane;
        const float4* kr = (const float4*)(k_att + j * DZ);
        float acc = 0.f;
#pragma unroll
        for (int u = 0; u < 8; ++u) {
            float4 kk = kr[u];
            acc += kk.x * qreg[u].x + kk.y * qreg[u].y + kk.z * qreg[u].z + kk.w * qreg[u].w;
        }
        sc[wv][j] = acc;
        m = fmaxf(m, acc);
    }
    m = wave_reduce_max(m);
    float denom = 0.f;
#pragma unroll 2
    for (int t = 0; t < 31; ++t) {
        int j = t * 64 + lane;
        float e = __expf(sc[wv][j] - m);
        sc[wv][j] = e;
        denom += e;
    }
    if (lane < 16) {
        int j = 31 * 64 + lane;
        float e = __expf(sc[wv][j] - m);
        sc[wv][j] = e;
        denom += e;
    }
    denom = wave_reduce_sum(denom);
    __syncthreads();

    // ---- Phase C: agg[c] = sum_j e_j * lm_feature[j][c] (coalesced) ----
    const int half = lane >> 5, c = lane & 31;
    float a = 0.f;
#pragma unroll 4
    for (int t = 0; t < N1v / 2; ++t) {
        int j = 2 * t + half;
        a += sc[wv][j] * lm_feature[j * DZ + c];
    }
    a += __shfl_xor(a, 32, 64);

    float td = tg_delay[i];
    float al = alpha[0], be = beta[0];
    float r2t0 = __expf(-gamma_2[0] * (al * td + be));
    float r2t1 = __expf(-gamma_3[0] * (al * td + be));
    __syncthreads();

    // ---- h0, tf1, h1, tf2 ----
    if (lane < DZ) {
        float tgf0 = (lane < DIN) ? xr[lane] : 0.f;
        float h0 = (tgf0 + a / denom + r2t0 * router_0[lane]) / (2.f + r2t0);
        vbuf[wv][lane] = h0;
    }
    __syncthreads();
    float tf1 = 0.f, tf2 = 0.f;
    if (lane < DZ) {
        float acc = w1_b[lane];
#pragma unroll
        for (int d = 0; d < DZ; ++d) acc += vbuf[wv][d] * w1_w[d * DZ + lane];
        tf1 = acc;
    }
    __syncthreads();
    if (lane < DZ) {
        float h1 = (tf1 + r2t1 * router_1[lane]) / (1.f + r2t1);
        vbuf[wv][lane] = h1;
    }
    __syncthreads();
    if (lane < DZ) {
        float acc = w2_b[lane];
#pragma unroll
        for (int d = 0; d < DZ; ++d) acc += vbuf[wv][d] * w2_w[d * DZ + lane];
        tf2 = acc;
    }
    __syncthreads();

    // ---- final_tg_feature = [tg_X | tf1 | tf2] -> vbuf[0..93] + global ----
    if (lane < DIN) vbuf[wv][lane] = xr[lane];
    if (lane < DZ) {
        vbuf[wv][DIN + lane] = tf1;
        vbuf[wv][DIN + DZ + lane] = tf2;
    }
    __syncthreads();
    for (int d = lane; d < DQ; d += 64) ftf_out[i * DQ + d] = vbuf[wv][d];

    // ---- Phase E: pq = (ftf @ pred_qw + pred_qb) / TEMP ----
    if (lane < DZ) {
        float acc = pred_qb[lane];
#pragma unroll
        for (int d = 0; d < DQ; ++d) acc += vbuf[wv][d] * pred_qw[d * DZ + lane];
        vbuf[wv][96 + lane] = acc * INV_TEMP;
    }
    __syncthreads();
#pragma unroll
    for (int u = 0; u < 8; ++u) qreg[u] = *(const float4*)&vbuf[wv][96 + u * 4];

    // ---- Phase F: second attention vs pk, aggregate pv ----
    float m2 = -1e30f;
#pragma unroll 2
    for (int t = 0; t < 31; ++t) {
        int j = t * 64 + lane;
        const float4* kr = (const float4*)(pk + j * DZ);
        float acc = 0.f;
#pragma unroll
        for (int u = 0; u < 8; ++u) {
            float4 kk = kr[u];
            acc += kk.x * qreg[u].x + kk.y * qreg[u].y + kk.z * qreg[u].z + kk.w * qreg[u].w;
        }
        sc[wv][j] = acc;
        m2 = fmaxf(m2, acc);
    }
    if (lane < 16) {
        int j = 31 * 64 + lane;
        const float4* kr = (const float4*)(pk + j * DZ);
        float acc = 0.f;
#pragma unroll
        for (int u = 0; u < 8; ++u) {
            float4 kk = kr[u];
            acc += kk.x * qreg[u].x + kk.y * qreg[u].y + kk.z * qreg[u].z + kk.w * qreg[u].w;
        }
        sc[wv][j] = acc;
        m2 = fmaxf(m2, acc);
    }
    m2 = wave_reduce_max(m2);
    float den2 = 0.f, y0 = 0.f, y1 = 0.f;
#pragma unroll 2
    for (int t = 0; t < 31; ++t) {
        int j = t * 64 + lane;
        float e = __expf(sc[wv][j] - m2);
        den2 += e;
        float2 pvj = *(const float2*)(pv + 2 * j);
        y0 += e * pvj.x;
        y1 += e * pvj.y;
    }
    if (lane < 16) {
        int j = 31 * 64 + lane;
        float e = __expf(sc[wv][j] - m2);
        den2 += e;
        float2 pvj = *(const float2*)(pv + 2 * j);
        y0 += e * pvj.x;
        y1 += e * pvj.y;
    }
    den2 = wave_reduce_sum(den2);
    y0 = wave_reduce_sum(y0);
    y1 = wave_reduce_sum(y1);
    if (lane == 0) {
        y_out[2 * i] = y0 / den2;
        y_out[2 * i + 1] = y1 / den2;
    }
}

extern "C" void kernel_launch(void* const* d_in, const int* in_sizes, int n_in,
                              void* d_out, int out_size, void* d_ws, size_t ws_size,
                              hipStream_t stream) {
    const float* lm_X     = (const float*)d_in[0];
    const float* lm_Y     = (const float*)d_in[1];
    const float* tg_X     = (const float*)d_in[2];
    // d_in[3] tg_Y unused
    const float* lm_delay = (const float*)d_in[4];
    const float* tg_delay = (const float*)d_in[5];
    const float* gamma_1  = (const float*)d_in[6];
    const float* gamma_2  = (const float*)d_in[7];
    const float* gamma_3  = (const float*)d_in[8];
    const float* alpha    = (const float*)d_in[9];
    const float* beta     = (const float*)d_in[10];
    const float* att_qw   = (const float*)d_in[11];
    const float* att_qb   = (const float*)d_in[12];
    const float* att_kw   = (const float*)d_in[13];
    const float* att_kb   = (const float*)d_in[14];
    // d_in[15] att_vw, d_in[16] att_vb unused by reference
    const float* w1_w     = (const float*)d_in[17];
    const float* w1_b     = (const float*)d_in[18];
    const float* w2_w     = (const float*)d_in[19];
    const float* w2_b     = (const float*)d_in[20];
    const float* pred_qw  = (const float*)d_in[21];
    const float* pred_qb  = (const float*)d_in[22];
    const float* pred_kw  = (const float*)d_in[23];
    const float* pred_kb  = (const float*)d_in[24];
    const float* pred_vw  = (const float*)d_in[25];
    const float* pred_vb  = (const float*)d_in[26];

    float* ws          = (float*)d_ws;
    float* lm_feature  = ws;            // 64000
    float* k_att       = ws + 64000;    // 64000
    float* pk          = ws + 128000;   // 64000
    float* pv          = ws + 192000;   // 4000
    float* delay_score = ws + 196000;   // 2000
    float* router_0    = ws + 198000;   // 32
    float* router_1    = ws + 198032;   // 32

    float* y_out   = (float*)d_out;        // 4000 x 2
    float* ftf_out = y_out + 2 * N2v;      // 4000 x 94

    prep_kernel<<<(N1v * DZ + 255) / 256, 256, 0, stream>>>(
        lm_X, lm_Y, lm_delay, att_kw, att_kb, pred_kw, pred_kb,
        pred_vw, pred_vb, gamma_1, alpha, beta,
        lm_feature, k_att, pk, pv, delay_score);

    router_kernel<<<1, 256, 0, stream>>>(
        lm_feature, delay_score, w1_w, w1_b, router_0, router_1);

    main_kernel<<<N2v / 4, 256, 0, stream>>>(
        tg_X, tg_delay, att_qw, att_qb, w1_w, w1_b, w2_w, w2_b,
        pred_qw, pred_qb, gamma_2, gamma_3, alpha, beta,
        lm_feature, k_att, pk, pv, router_0, router_1,
        y_out, ftf_out);
}

// Round 2
// 182.999 us; speedup vs baseline: 1.8369x; 1.8369x over previous
//
#include <hip/hip_runtime.h>

#define N1v 2000
#define N2v 4000
#define DIN 30
#define DZ 32
#define DQ 94
#define INV_TEMP 0.17677669529663687f  // 1/sqrt(32)

__device__ __forceinline__ float wave_reduce_sum(float v) {
#pragma unroll
    for (int off = 32; off; off >>= 1) v += __shfl_xor(v, off, 64);
    return v;
}
__device__ __forceinline__ float wave_reduce_max(float v) {
#pragma unroll
    for (int off = 32; off; off >>= 1) v = fmaxf(v, __shfl_xor(v, off, 64));
    return v;
}

// ---------------------------------------------------------------------------
// Kernel 1: landmark projections (TRANSPOSED k/pk output), features, pv, delay
// block = 256 threads = 8 rows x 32 channels; grid = 250
// ---------------------------------------------------------------------------
__global__ __launch_bounds__(256) void prep_kernel(
    const float* __restrict__ lm_X, const float* __restrict__ lm_Y,
    const float* __restrict__ lm_delay,
    const float* __restrict__ att_kw, const float* __restrict__ att_kb,
    const float* __restrict__ pred_kw, const float* __restrict__ pred_kb,
    const float* __restrict__ pred_vw, const float* __restrict__ pred_vb,
    const float* __restrict__ gamma_1, const float* __restrict__ alpha,
    const float* __restrict__ beta,
    float* __restrict__ lm_feature, float* __restrict__ k_t,
    float* __restrict__ pk_t, float* __restrict__ pv,
    float* __restrict__ delay_score)
{
    __shared__ float sh_x[8][DIN];
    __shared__ float sh_k[DZ][9];
    __shared__ float sh_p[DZ][9];
    const int t = threadIdx.x;
    const int base = blockIdx.x * 8;
    if (t < 8 * DIN) sh_x[t / DIN][t % DIN] = lm_X[base * DIN + t];
    __syncthreads();
    const int ty = t >> 5, c = t & 31;
    const int row = base + ty;
    float kacc = att_kb[c], pacc = pred_kb[c];
#pragma unroll
    for (int d = 0; d < DIN; ++d) {
        float x = sh_x[ty][d];
        kacc += x * att_kw[d * DZ + c];
        pacc += x * pred_kw[d * DZ + c];
    }
    sh_k[c][ty] = kacc;
    sh_p[c][ty] = pacc;
    lm_feature[row * DZ + c] = (c < DIN) ? sh_x[ty][c] : lm_Y[row * 2 + (c - DIN)];
    if (c < 2) {
        pv[row * 2 + c] = lm_Y[row * 2] * pred_vw[c] +
                          lm_Y[row * 2 + 1] * pred_vw[2 + c] + pred_vb[c];
    }
    if (c == 0) {
        delay_score[row] = __expf(-gamma_1[0] * (alpha[0] * lm_delay[row] + beta[0]));
    }
    __syncthreads();
    const int oc = t >> 3, orow = t & 7;   // transpose store: k_t[32][2000]
    k_t[oc * N1v + base + orow] = sh_k[oc][orow];
    pk_t[oc * N1v + base + orow] = sh_p[oc][orow];
}

// ---------------------------------------------------------------------------
// Kernel 2: router_0 (column mean), router_1 = h_r @ w1_w + w1_b
// ---------------------------------------------------------------------------
__global__ __launch_bounds__(256) void router_kernel(
    const float* __restrict__ lm_feature, const float* __restrict__ delay_score,
    const float* __restrict__ w1_w, const float* __restrict__ w1_b,
    float* __restrict__ router_0, float* __restrict__ router_1)
{
    __shared__ float ps[8][DZ];
    __shared__ float pw[8][DZ];
    __shared__ float pd[8];
    __shared__ float hr[DZ];
    int t = threadIdx.x;
    int c = t & 31, g = t >> 5;
    float s = 0.f, wsum = 0.f, sd = 0.f;
    for (int r = g; r < N1v; r += 8) {
        float f = lm_feature[r * DZ + c];
        float ds = delay_score[r];
        s += f;
        wsum += ds * f;
        if (c == 0) sd += ds;
    }
    ps[g][c] = s;
    pw[g][c] = wsum;
    if (c == 0) pd[g] = sd;
    __syncthreads();
    if (t < DZ) {
        float S = 0.f, W = 0.f, Sd = 0.f;
#pragma unroll
        for (int g2 = 0; g2 < 8; ++g2) { S += ps[g2][t]; W += pw[g2][t]; Sd += pd[g2]; }
        float r0 = S / (float)N1v;
        router_0[t] = r0;
        hr[t] = (r0 + W) / (1.f + Sd);
    }
    __syncthreads();
    if (t < DZ) {
        float acc = w1_b[t];
#pragma unroll
        for (int d = 0; d < DZ; ++d) acc += hr[d] * w1_w[d * DZ + t];
        router_1[t] = acc;
    }
}

// ---------------------------------------------------------------------------
// Kernel 3: fused per-target pipeline. wave = 2 targets, block = 4 waves,
// grid = 500. Online softmax over 8 tiles of 256 landmarks; all small
// broadcasts via readlane-shfl; e exchanged through LDS tiles.
// ---------------------------------------------------------------------------
__global__ __launch_bounds__(256) void main_kernel(
    const float* __restrict__ tg_X, const float* __restrict__ tg_delay,
    const float* __restrict__ att_qw, const float* __restrict__ att_qb,
    const float* __restrict__ w1_w, const float* __restrict__ w1_b,
    const float* __restrict__ w2_w, const float* __restrict__ w2_b,
    const float* __restrict__ pred_qw, const float* __restrict__ pred_qb,
    const float* __restrict__ gamma_2, const float* __restrict__ gamma_3,
    const float* __restrict__ alpha, const float* __restrict__ beta,
    const float* __restrict__ k_t, const float* __restrict__ pk_t,
    const float* __restrict__ lm_feature, const float* __restrict__ pv,
    const float* __restrict__ router_0, const float* __restrict__ router_1,
    float* __restrict__ y_out, float* __restrict__ ftf_out)
{
    __shared__ __align__(16) float e_lds[4][2][256];
    __shared__ __align__(16) float exch[4][2][DZ];
    const int wv = threadIdx.x >> 6;
    const int lane = threadIdx.x & 63;
    const int i0 = __builtin_amdgcn_readfirstlane((blockIdx.x * 4 + wv) * 2);
    const int half = lane >> 5, c = lane & 31;
    const int i = i0 + half;

    // own-target features for this lane's channel
    float xreg = (c < DIN) ? tg_X[i * DIN + c] : 0.f;

    // ---- q projection via readlane broadcasts ----
    float q = att_qb[c];
#pragma unroll
    for (int d = 0; d < DIN; ++d) {
        float x0 = __shfl(xreg, d, 64);
        float x1 = __shfl(xreg, 32 + d, 64);
        q += (half ? x1 : x0) * att_qw[d * DZ + c];
    }
    float qreg = q * INV_TEMP;

    // ---- attention 1: online softmax + feature aggregation ----
    const int r0 = lane * 4;
    const int rg = lane >> 3, cq = lane & 7;
    float mrun[2] = {-1e30f, -1e30f};
    float den[2] = {0.f, 0.f};
    float agg[2][4] = {{0.f,0.f,0.f,0.f},{0.f,0.f,0.f,0.f}};

    for (int t = 0; t < 8; ++t) {
        const int tb = t << 8;
        const int rbase = tb + r0;
        const int rld = (rbase <= N1v - 4) ? rbase : (N1v - 4);
        const bool dead = (rbase >= N1v);
        float s[2][4] = {{0.f,0.f,0.f,0.f},{0.f,0.f,0.f,0.f}};
        const float* kp = k_t + rld;
#pragma unroll
        for (int cc = 0; cc < DZ; ++cc) {
            float4 kt = *(const float4*)(kp + cc * N1v);
            float q0 = __shfl(qreg, cc, 64);
            float q1 = __shfl(qreg, 32 + cc, 64);
            s[0][0] += q0 * kt.x; s[0][1] += q0 * kt.y; s[0][2] += q0 * kt.z; s[0][3] += q0 * kt.w;
            s[1][0] += q1 * kt.x; s[1][1] += q1 * kt.y; s[1][2] += q1 * kt.z; s[1][3] += q1 * kt.w;
        }
        if (dead) {
#pragma unroll
            for (int k = 0; k < 4; ++k) { s[0][k] = -1e30f; s[1][k] = -1e30f; }
        }
        float scv[2];
#pragma unroll
        for (int m = 0; m < 2; ++m) {
            float tmax = fmaxf(fmaxf(s[m][0], s[m][1]), fmaxf(s[m][2], s[m][3]));
            tmax = wave_reduce_max(tmax);
            float nm = fmaxf(mrun[m], tmax);
            float sc = __expf(mrun[m] - nm);
            mrun[m] = nm;
            scv[m] = sc;
            float e0 = __expf(s[m][0] - nm), e1 = __expf(s[m][1] - nm);
            float e2 = __expf(s[m][2] - nm), e3 = __expf(s[m][3] - nm);
            den[m] = den[m] * sc + ((e0 + e1) + (e2 + e3));
            float4 ev = {e0, e1, e2, e3};
            *(float4*)&e_lds[wv][m][r0] = ev;
        }
        __syncthreads();
        // rescale old aggregate, then accumulate this tile (8 rows/iter)
#pragma unroll
        for (int m = 0; m < 2; ++m) {
#pragma unroll
            for (int k = 0; k < 4; ++k) agg[m][k] *= scv[m];
        }
        const int pmax = (t == 7) ? 26 : 32;   // tile 7 has 208 valid rows
        const float* lmp = lm_feature + tb * DZ + rg * DZ + cq * 4;
        for (int p = 0; p < pmax; ++p) {
            int j = (p << 3) + rg;
            float4 lmv = *(const float4*)(lmp + (p << 3) * DZ);
            float e0 = e_lds[wv][0][j];
            float e1 = e_lds[wv][1][j];
            agg[0][0] += e0 * lmv.x; agg[0][1] += e0 * lmv.y;
            agg[0][2] += e0 * lmv.z; agg[0][3] += e0 * lmv.w;
            agg[1][0] += e1 * lmv.x; agg[1][1] += e1 * lmv.y;
            agg[1][2] += e1 * lmv.z; agg[1][3] += e1 * lmv.w;
        }
        __syncthreads();
    }

    // reduce aggregate across the 8 row-groups; reduce denominators
#pragma unroll
    for (int m = 0; m < 2; ++m) {
#pragma unroll
        for (int off = 8; off <= 32; off <<= 1) {
#pragma unroll
            for (int k = 0; k < 4; ++k) agg[m][k] += __shfl_xor(agg[m][k], off, 64);
        }
        den[m] = wave_reduce_sum(den[m]);
    }
    if (lane < 8) {
        float4 a0 = {agg[0][0], agg[0][1], agg[0][2], agg[0][3]};
        float4 a1 = {agg[1][0], agg[1][1], agg[1][2], agg[1][3]};
        *(float4*)&exch[wv][0][lane * 4] = a0;
        *(float4*)&exch[wv][1][lane * 4] = a1;
    }
    __syncthreads();
    float aggc = exch[wv][half][c];
    float denh = half ? den[1] : den[0];

    // ---- graph steps: h0 -> tf1 -> h1 -> tf2 ----
    const float al = alpha[0], be = beta[0];
    const float td = tg_delay[i];
    float r2t0 = __expf(-gamma_2[0] * (al * td + be));
    float r2t1 = __expf(-gamma_3[0] * (al * td + be));
    float h0 = (xreg + aggc / denh + r2t0 * router_0[c]) / (2.f + r2t0);

    float tf1 = w1_b[c];
#pragma unroll
    for (int d = 0; d < DZ; ++d) {
        float a0 = __shfl(h0, d, 64);
        float a1 = __shfl(h0, 32 + d, 64);
        tf1 += (half ? a1 : a0) * w1_w[d * DZ + c];
    }
    float h1 = (tf1 + r2t1 * router_1[c]) / (1.f + r2t1);
    float tf2 = w2_b[c];
#pragma unroll
    for (int d = 0; d < DZ; ++d) {
        float a0 = __shfl(h1, d, 64);
        float a1 = __shfl(h1, 32 + d, 64);
        tf2 += (half ? a1 : a0) * w2_w[d * DZ + c];
    }

    // ---- final_tg_feature = [tg_X | tf1 | tf2] ----
    if (c < DIN) ftf_out[i * DQ + c] = xreg;
    ftf_out[i * DQ + DIN + c] = tf1;
    ftf_out[i * DQ + DIN + DZ + c] = tf2;

    // ---- pq projection (94-dim, via readlane) ----
    float pq = pred_qb[c];
#pragma unroll
    for (int d = 0; d < DIN; ++d) {
        float a0 = __shfl(xreg, d, 64);
        float a1 = __shfl(xreg, 32 + d, 64);
        pq += (half ? a1 : a0) * pred_qw[d * DZ + c];
    }
#pragma unroll
    for (int d = 0; d < DZ; ++d) {
        float a0 = __shfl(tf1, d, 64);
        float a1 = __shfl(tf1, 32 + d, 64);
        pq += (half ? a1 : a0) * pred_qw[(DIN + d) * DZ + c];
    }
#pragma unroll
    for (int d = 0; d < DZ; ++d) {
        float a0 = __shfl(tf2, d, 64);
        float a1 = __shfl(tf2, 32 + d, 64);
        pq += (half ? a1 : a0) * pred_qw[(DIN + DZ + d) * DZ + c];
    }
    float pqreg = pq * INV_TEMP;

    // ---- attention 2: online softmax, pv aggregation fully in registers ----
    float m2[2] = {-1e30f, -1e30f};
    float den2[2] = {0.f, 0.f};
    float y0[2] = {0.f, 0.f}, y1[2] = {0.f, 0.f};
    for (int t = 0; t < 8; ++t) {
        __syncthreads();   // keep waves tile-locked for L1 reuse
        const int tb = t << 8;
        const int rbase = tb + r0;
        const int rld = (rbase <= N1v - 4) ? rbase : (N1v - 4);
        const bool dead = (rbase >= N1v);
        float s[2][4] = {{0.f,0.f,0.f,0.f},{0.f,0.f,0.f,0.f}};
        const float* kp = pk_t + rld;
#pragma unroll
        for (int cc = 0; cc < DZ; ++cc) {
            float4 kt = *(const float4*)(kp + cc * N1v);
            float q0 = __shfl(pqreg, cc, 64);
            float q1 = __shfl(pqreg, 32 + cc, 64);
            s[0][0] += q0 * kt.x; s[0][1] += q0 * kt.y; s[0][2] += q0 * kt.z; s[0][3] += q0 * kt.w;
            s[1][0] += q1 * kt.x; s[1][1] += q1 * kt.y; s[1][2] += q1 * kt.z; s[1][3] += q1 * kt.w;
        }
        if (dead) {
#pragma unroll
            for (int k = 0; k < 4; ++k) { s[0][k] = -1e30f; s[1][k] = -1e30f; }
        }
        float4 pva = *(const float4*)(pv + 2 * rld);
        float4 pvb = *(const float4*)(pv + 2 * rld + 4);
#pragma unroll
        for (int m = 0; m < 2; ++m) {
            float tmax = fmaxf(fmaxf(s[m][0], s[m][1]), fmaxf(s[m][2], s[m][3]));
            tmax = wave_reduce_max(tmax);
            float nm = fmaxf(m2[m], tmax);
            float sc = __expf(m2[m] - nm);
            m2[m] = nm;
            float e0 = __expf(s[m][0] - nm), e1 = __expf(s[m][1] - nm);
            float e2 = __expf(s[m][2] - nm), e3 = __expf(s[m][3] - nm);
            den2[m] = den2[m] * sc + ((e0 + e1) + (e2 + e3));
            y0[m] = y0[m] * sc + e0 * pva.x + e1 * pva.z + e2 * pvb.x + e3 * pvb.z;
            y1[m] = y1[m] * sc + e0 * pva.y + e1 * pva.w + e2 * pvb.y + e3 * pvb.w;
        }
    }
#pragma unroll
    for (int m = 0; m < 2; ++m) {
        den2[m] = wave_reduce_sum(den2[m]);
        y0[m] = wave_reduce_sum(y0[m]);
        y1[m] = wave_reduce_sum(y1[m]);
    }
    if (lane == 0) {
        y_out[2 * i0 + 0] = y0[0] / den2[0];
        y_out[2 * i0 + 1] = y1[0] / den2[0];
        y_out[2 * i0 + 2] = y0[1] / den2[1];
        y_out[2 * i0 + 3] = y1[1] / den2[1];
    }
}

extern "C" void kernel_launch(void* const* d_in, const int* in_sizes, int n_in,
                              void* d_out, int out_size, void* d_ws, size_t ws_size,
                              hipStream_t stream) {
    const float* lm_X     = (const float*)d_in[0];
    const float* lm_Y     = (const float*)d_in[1];
    const float* tg_X     = (const float*)d_in[2];
    const float* lm_delay = (const float*)d_in[4];
    const float* tg_delay = (const float*)d_in[5];
    const float* gamma_1  = (const float*)d_in[6];
    const float* gamma_2  = (const float*)d_in[7];
    const float* gamma_3  = (const float*)d_in[8];
    const float* alpha    = (const float*)d_in[9];
    const float* beta     = (const float*)d_in[10];
    const float* att_qw   = (const float*)d_in[11];
    const float* att_qb   = (const float*)d_in[12];
    const float* att_kw   = (const float*)d_in[13];
    const float* att_kb   = (const float*)d_in[14];
    const float* w1_w     = (const float*)d_in[17];
    const float* w1_b     = (const float*)d_in[18];
    const float* w2_w     = (const float*)d_in[19];
    const float* w2_b     = (const float*)d_in[20];
    const float* pred_qw  = (const float*)d_in[21];
    const float* pred_qb  = (const float*)d_in[22];
    const float* pred_kw  = (const float*)d_in[23];
    const float* pred_kb  = (const float*)d_in[24];
    const float* pred_vw  = (const float*)d_in[25];
    const float* pred_vb  = (const float*)d_in[26];

    float* ws          = (float*)d_ws;
    float* k_t         = ws;            // 32 x 2000
    float* pk_t        = ws + 64000;    // 32 x 2000
    float* lm_feature  = ws + 128000;   // 2000 x 32
    float* pv          = ws + 192000;   // 2000 x 2
    float* delay_score = ws + 196000;   // 2000
    float* router_0    = ws + 198000;   // 32
    float* router_1    = ws + 198032;   // 32

    float* y_out   = (float*)d_out;        // 4000 x 2
    float* ftf_out = y_out + 2 * N2v;      // 4000 x 94

    prep_kernel<<<N1v / 8, 256, 0, stream>>>(
        lm_X, lm_Y, lm_delay, att_kw, att_kb, pred_kw, pred_kb,
        pred_vw, pred_vb, gamma_1, alpha, beta,
        lm_feature, k_t, pk_t, pv, delay_score);

    router_kernel<<<1, 256, 0, stream>>>(
        lm_feature, delay_score, w1_w, w1_b, router_0, router_1);

    main_kernel<<<N2v / 8, 256, 0, stream>>>(
        tg_X, tg_delay, att_qw, att_qb, w1_w, w1_b, w2_w, w2_b,
        pred_qw, pred_qb, gamma_2, gamma_3, alpha, beta,
        k_t, pk_t, lm_feature, pv, router_0, router_1,
        y_out, ftf_out);
}